// Round 1
// baseline (279.524 us; speedup 1.0000x reference)
//
#include <hip/hip_runtime.h>

// MobileMQA: B=8, C=256, H=W=64, NUM_HEADS=4, hd=64, ds=2
// R8: occupancy push — k_fused n-tile 64->32 (grid 1024, 4 blocks/CU target,
//     __launch_bounds__(256,4)), no explicit K/V double-copy prefetch,
//     den folded into PV via ones-row MFMA (removes den VALU adds + shfl reduce),
//     s_setprio around PV cluster. k_gemm_kv K/V stores restaged via LDS
//     (coalesced uint4). k_xnt xdsT store remapped m-row-major (coalesced).

#define CNT_INV (1.0f/1048576.0f)
#define EPSV 1e-5f
#define QSCALE 0.18033688f   // 0.125 * log2(e): folded into Q; exp becomes v_exp_f32(S)

// workspace layout (float offsets)
#define WS_STATS 0                    // 64
#define WS_XNT   64                   // bf16 xnT [b][n][c]  = 4,194,304 f
#define WS_XDS   4194368              // bf16 xdsT [b][m][c] = 1,048,576 f
#define WS_K     5242944              // bf16 k   [b][m][d]  = 262,144 f
#define WS_V     5505088              // bf16 vT  [b][d][m]  = 262,144 f
#define WS_WQB   5767232              // bf16 wq  [o][c]     = 32,768 f
#define WS_WKV   5800000              // bf16 [wk;wv]        = 16,384 f
#define WS_WOB   5816384              // bf16 wo  [o][c]     = 32,768 f

typedef __attribute__((ext_vector_type(8))) short bf8_t;   // 8 bf16 MFMA A/B frag
typedef __attribute__((ext_vector_type(4))) float f4_t;    // MFMA C/D frag

static __device__ __forceinline__ unsigned fbits(float f) {
  union { float f; unsigned u; } v; v.f = f; return v.u;
}
static __device__ __forceinline__ unsigned short f2bf(float f) {  // RNE
  unsigned u = fbits(f);
  return (unsigned short)((u + 0x7fffu + ((u >> 16) & 1u)) >> 16);
}
static __device__ __forceinline__ unsigned pk_rnd(float a, float b) {
  return __builtin_amdgcn_perm(fbits(b) + 0x8000u, fbits(a) + 0x8000u, 0x07060302u);
}
static __device__ __forceinline__ unsigned pk_tr(float a, float b) {
  return __builtin_amdgcn_perm(fbits(b), fbits(a), 0x07060302u);
}
static __device__ __forceinline__ float bf2f(unsigned short h) {
  union { unsigned u; float f; } v; v.u = ((unsigned)h) << 16; return v.f;
}
static __device__ __forceinline__ float fexp2(float x) {   // 2^x, raw v_exp_f32
  float r; asm("v_exp_f32 %0, %1" : "=v"(r) : "v"(x)); return r;
}

// ---------------- merged: weight prep (blocks >= 512) + stats (blocks < 512) ----------------
__global__ __launch_bounds__(256) void k_prep_stats(const float* __restrict__ x,
                                                    const float* __restrict__ wq,
                                                    const float* __restrict__ wk,
                                                    const float* __restrict__ wv,
                                                    const float* __restrict__ wo,
                                                    float* __restrict__ stats,
                                                    unsigned short* __restrict__ wqb,
                                                    unsigned short* __restrict__ wkvb,
                                                    unsigned short* __restrict__ wob) {
  const int blk = blockIdx.x;
  const int t = threadIdx.x;
  if (blk < 512) {
    const int b = blk >> 6;
    const int chunk = blk & 63;
    const float4* xb = (const float4*)(x + (size_t)b * 1048576 + (size_t)chunk * 16384);
    float s = 0.f, s2 = 0.f;
#pragma unroll
    for (int it = 0; it < 16; ++it) {
      float4 v = xb[it * 256 + t];
      s  += v.x + v.y + v.z + v.w;
      s2 += v.x * v.x + v.y * v.y + v.z * v.z + v.w * v.w;
    }
#pragma unroll
    for (int o = 32; o > 0; o >>= 1) {
      s  += __shfl_down(s, o);
      s2 += __shfl_down(s2, o);
    }
    __shared__ float red[8];
    const int wid = t >> 6;
    if ((t & 63) == 0) { red[wid] = s; red[4 + wid] = s2; }
    __syncthreads();
    if (t == 0) {
      atomicAdd(&stats[b * 2 + 0], red[0] + red[1] + red[2] + red[3]);
      atomicAdd(&stats[b * 2 + 1], red[4] + red[5] + red[6] + red[7]);
    }
  } else {
    const int idx = (blk - 512) * 256 + t;
    if (idx < 65536) wqb[idx] = f2bf(wq[idx]);
    else if (idx < 81920) wkvb[idx - 65536] = f2bf(wk[idx - 65536]);
    else if (idx < 98304) wkvb[idx - 65536] = f2bf(wv[idx - 81920]);
    else if (idx < 163840) wob[idx - 98304] = f2bf(wo[idx - 98304]);
  }
}

// ---------------- normalize + transpose + fused 2x2 pool ----------------
__global__ __launch_bounds__(256) void k_xnt(const float* __restrict__ x,
                                             const float* __restrict__ gnw,
                                             const float* __restrict__ gnb,
                                             const float* __restrict__ stats,
                                             unsigned short* __restrict__ xnT,
                                             unsigned short* __restrict__ xdsT) {
  __shared__ unsigned short T[128][72];   // [n_local][c_local]
  const int t = threadIdx.x;
  const int b = blockIdx.z, c0 = blockIdx.y * 64, hp = blockIdx.x;
  const int n0 = hp * 128;
  const float mu = stats[b * 2 + 0] * CNT_INV;
  const float rstd = rsqrtf(stats[b * 2 + 1] * CNT_INV - mu * mu + EPSV);
  const int n4 = (t & 31) * 4, cl = t >> 5;
#pragma unroll
  for (int p = 0; p < 8; ++p) {
    const int c = c0 + p * 8 + cl;
    const float gw = gnw[c] * rstd;
    const float gb = gnb[c] - mu * rstd * gnw[c];
    float4 v = *(const float4*)&x[(size_t)(b * 256 + c) * 4096 + n0 + n4];
    T[n4 + 0][p * 8 + cl] = f2bf(v.x * gw + gb);
    T[n4 + 1][p * 8 + cl] = f2bf(v.y * gw + gb);
    T[n4 + 2][p * 8 + cl] = f2bf(v.z * gw + gb);
    T[n4 + 3][p * 8 + cl] = f2bf(v.w * gw + gb);
  }
  __syncthreads();
  {  // write xnT: 128 rows x 64 c
    const int r = t >> 1, ch = (t & 1) * 32;
    unsigned short* dst = xnT + ((size_t)b * 4096 + n0 + r) * 256 + c0 + ch;
#pragma unroll
    for (int u = 0; u < 4; ++u)
      *(uint4*)(dst + u * 8) = *(const uint4*)&T[r][ch + u * 8];
  }
  {  // fused pool: 32 m x 64 c — m-row-major thread map for coalesced store
    const int wd = t >> 3, c8 = (t & 7) * 8;
    uint4 u0 = *(const uint4*)&T[2 * wd][c8];
    uint4 u1 = *(const uint4*)&T[2 * wd + 1][c8];
    uint4 u2 = *(const uint4*)&T[64 + 2 * wd][c8];
    uint4 u3 = *(const uint4*)&T[64 + 2 * wd + 1][c8];
    const unsigned* p0 = (const unsigned*)&u0; const unsigned* p1 = (const unsigned*)&u1;
    const unsigned* p2 = (const unsigned*)&u2; const unsigned* p3 = (const unsigned*)&u3;
    unsigned outp[4];
#pragma unroll
    for (int i = 0; i < 4; ++i) {
      float lo = (bf2f((unsigned short)p0[i]) + bf2f((unsigned short)p1[i]) +
                  bf2f((unsigned short)p2[i]) + bf2f((unsigned short)p3[i])) * 0.25f;
      float hi = (bf2f((unsigned short)(p0[i] >> 16)) + bf2f((unsigned short)(p1[i] >> 16)) +
                  bf2f((unsigned short)(p2[i] >> 16)) + bf2f((unsigned short)(p3[i] >> 16))) * 0.25f;
      outp[i] = pk_rnd(lo, hi);
    }
    *(uint4*)(xdsT + ((size_t)b * 1024 + hp * 32 + wd) * 256 + c0 + c8) = *(uint4*)outp;
  }
}

// ---------------- K/V gemm (MFMA): k[b][m][d], vT[b][d][m] bf16, LDS-staged stores ----------------
__global__ __launch_bounds__(256) void k_gemm_kv(const unsigned short* __restrict__ wkvb,
                                                 const unsigned short* __restrict__ xdsT,
                                                 unsigned short* __restrict__ kbf,
                                                 unsigned short* __restrict__ vtbf) {
  __shared__ __align__(16) unsigned short kv[2][64][72];   // [0]=K [m][d], [1]=V [d][m]
  const int t = threadIdx.x;
  const int w = t >> 6, l = t & 63, lane16 = l & 15, quad = l >> 4;
  const int m0 = blockIdx.x * 64, b = blockIdx.y;
  const unsigned short* Abase = wkvb + (size_t)(w * 32 + lane16) * 256 + quad * 8;
  const unsigned short* Bbase = xdsT + ((size_t)b * 1024 + m0 + lane16) * 256 + quad * 8;
  f4_t acc[2][4];
#pragma unroll
  for (int i = 0; i < 2; ++i)
#pragma unroll
    for (int j = 0; j < 4; ++j) acc[i][j] = (f4_t){0.f, 0.f, 0.f, 0.f};
  bf8_t Ac[2], Bc[4];
#pragma unroll
  for (int og = 0; og < 2; ++og) Ac[og] = *(const bf8_t*)(Abase + (size_t)og * 16 * 256);
#pragma unroll
  for (int mg = 0; mg < 4; ++mg) Bc[mg] = *(const bf8_t*)(Bbase + (size_t)mg * 16 * 256);
  for (int kc = 0; kc < 256; kc += 32) {
    const int kn = (kc + 32) & 255;
    bf8_t An[2], Bn[4];
#pragma unroll
    for (int og = 0; og < 2; ++og) An[og] = *(const bf8_t*)(Abase + (size_t)og * 16 * 256 + kn);
#pragma unroll
    for (int mg = 0; mg < 4; ++mg) Bn[mg] = *(const bf8_t*)(Bbase + (size_t)mg * 16 * 256 + kn);
#pragma unroll
    for (int og = 0; og < 2; ++og)
#pragma unroll
      for (int mg = 0; mg < 4; ++mg)
        acc[og][mg] = __builtin_amdgcn_mfma_f32_16x16x32_bf16(Ac[og], Bc[mg], acc[og][mg], 0, 0, 0);
#pragma unroll
    for (int og = 0; og < 2; ++og) Ac[og] = An[og];
#pragma unroll
    for (int mg = 0; mg < 4; ++mg) Bc[mg] = Bn[mg];
  }
  if (w < 2) {  // K tile -> LDS [m][d]
#pragma unroll
    for (int og = 0; og < 2; ++og)
#pragma unroll
      for (int mg = 0; mg < 4; ++mg) {
        uint2 p;
        p.x = pk_rnd(acc[og][mg][0], acc[og][mg][1]);
        p.y = pk_rnd(acc[og][mg][2], acc[og][mg][3]);
        *(uint2*)&kv[0][mg * 16 + lane16][w * 32 + og * 16 + quad * 4] = p;
      }
  } else {  // V tile -> LDS [d][m]
#pragma unroll
    for (int og = 0; og < 2; ++og)
#pragma unroll
      for (int mg = 0; mg < 4; ++mg) {
        const int d0 = (w - 2) * 32 + og * 16 + quad * 4;
#pragma unroll
        for (int r = 0; r < 4; ++r)
          kv[1][d0 + r][mg * 16 + lane16] = f2bf(acc[og][mg][r]);
      }
  }
  __syncthreads();
  {  // coalesced writeout: row = 64 u16 = 8 uint4; thread t -> (row t>>2, 2x uint4)
    const int row = t >> 2, seg = (t & 3) * 16;
    uint4 k0 = *(const uint4*)&kv[0][row][seg];
    uint4 k1 = *(const uint4*)&kv[0][row][seg + 8];
    unsigned short* kd = kbf + (size_t)b * 65536 + (size_t)(m0 + row) * 64 + seg;
    *(uint4*)kd = k0; *(uint4*)(kd + 8) = k1;
    uint4 v0 = *(const uint4*)&kv[1][row][seg];
    uint4 v1 = *(const uint4*)&kv[1][row][seg + 8];
    unsigned short* vd = vtbf + (size_t)b * 65536 + (size_t)row * 1024 + m0 + seg;
    *(uint4*)vd = v0; *(uint4*)(vd + 8) = v1;
  }
}

// ---------------- fused Q-proj + attention + WO + residual ----------------
// R8: block = (b, 32-n tile), wave = head. grid 128x8 = 1024 blocks (4/CU target).
// LDS phases unioned (20,480 B total):
//   qst  [4][32][72] u16 (18,432 B)  — Q restage, per wave
//   plds [4][2][32][40] u16 (20,480 B) — P double-buffer, per wave
//   aos  [32][264] u16 (16,896 B)    — block-shared ao tile
// den folded into PV: Aone ones-row MFMA accumulates sum(P) in O4[qg][0] (quad 0 lanes).
__global__ __launch_bounds__(256, 4) void k_fused(const unsigned short* __restrict__ wqb,
                                                  const unsigned short* __restrict__ xnT,
                                                  const unsigned short* __restrict__ kbf,
                                                  const unsigned short* __restrict__ vtbf,
                                                  const unsigned short* __restrict__ wob,
                                                  const float* __restrict__ x,
                                                  const float* __restrict__ gamma,
                                                  float* __restrict__ outp) {
  __shared__ __align__(16) unsigned short smem[10240];   // 20,480 B
  const int t = threadIdx.x;
  const int w = t >> 6, l = t & 63, lane16 = l & 15, quad = l >> 4;
  const int n0 = blockIdx.x * 32, b = blockIdx.y;
  const int h = w;
  unsigned short* qst = smem + w * 2304;                               // [32][72]
  unsigned short (*plds)[32][40] = (unsigned short (*)[32][40])(smem + w * 2560);
  unsigned short (*aos)[264] = (unsigned short (*)[264])smem;

  const unsigned short* kb = kbf + (size_t)b * 65536;
  const unsigned short* vb = vtbf + (size_t)b * 65536;

  // ---- Phase 1: Q-proj 32q x 64d for this head, restage via LDS ----
  {
    const unsigned short* Abase = wqb + (size_t)(h * 64 + lane16) * 256 + quad * 8;
    const unsigned short* Bbase = xnT + ((size_t)b * 4096 + n0 + lane16) * 256 + quad * 8;
    f4_t qacc[4][2];
#pragma unroll
    for (int i = 0; i < 4; ++i)
#pragma unroll
      for (int j = 0; j < 2; ++j) qacc[i][j] = (f4_t){0.f, 0.f, 0.f, 0.f};
    for (int kc = 0; kc < 256; kc += 32) {
      bf8_t A[4], Bf[2];
#pragma unroll
      for (int og = 0; og < 4; ++og) A[og] = *(const bf8_t*)(Abase + (size_t)og * 16 * 256 + kc);
#pragma unroll
      for (int ng = 0; ng < 2; ++ng) Bf[ng] = *(const bf8_t*)(Bbase + (size_t)ng * 16 * 256 + kc);
#pragma unroll
      for (int og = 0; og < 4; ++og)
#pragma unroll
        for (int ng = 0; ng < 2; ++ng)
          qacc[og][ng] = __builtin_amdgcn_mfma_f32_16x16x32_bf16(A[og], Bf[ng], qacc[og][ng], 0, 0, 0);
    }
    // C-layout (row d = og*16+quad*4+r, col q = ng*16+lane16) -> qst[q][d]
#pragma unroll
    for (int og = 0; og < 4; ++og)
#pragma unroll
      for (int ng = 0; ng < 2; ++ng) {
        uint2 p;
        p.x = pk_rnd(qacc[og][ng][0] * QSCALE, qacc[og][ng][1] * QSCALE);
        p.y = pk_rnd(qacc[og][ng][2] * QSCALE, qacc[og][ng][3] * QSCALE);
        *(uint2*)&qst[(ng * 16 + lane16) * 72 + og * 16 + quad * 4] = p;
      }
  }
  bf8_t Qf[2][2];
#pragma unroll
  for (int qg = 0; qg < 2; ++qg)
#pragma unroll
    for (int dc = 0; dc < 2; ++dc)
      Qf[qg][dc] = *(const bf8_t*)&qst[(qg * 16 + lane16) * 72 + dc * 32 + quad * 8];
  __syncthreads();   // all waves read Q before plds overwrites qst space

  // ---- Phase 2: pipelined attention (PV lags S by one KV step) ----
  f4_t O[4][2];
#pragma unroll
  for (int dg = 0; dg < 4; ++dg)
#pragma unroll
    for (int qg = 0; qg < 2; ++qg) O[dg][qg] = (f4_t){0.f, 0.f, 0.f, 0.f};
  f4_t O4[2];
  O4[0] = (f4_t){0.f, 0.f, 0.f, 0.f};
  O4[1] = (f4_t){0.f, 0.f, 0.f, 0.f};
  // ones-row A fragment: A row = lane16, so lane16==0 (all quads) holds bf16 1.0 x8.
  // Output row 0 (quad0, reg0) accumulates sum_m P[q][m] = softmax denominator.
  const short onebf = (lane16 == 0) ? (short)0x3F80 : (short)0;
  const bf8_t Aone = {onebf, onebf, onebf, onebf, onebf, onebf, onebf, onebf};

#define SSTEP(KREG, BUF)                                                      \
  {                                                                           \
    _Pragma("unroll")                                                         \
    for (int qg = 0; qg < 2; ++qg) {                                          \
      _Pragma("unroll")                                                       \
      for (int s = 0; s < 2; ++s) {                                           \
        f4_t S = (f4_t){0.f, 0.f, 0.f, 0.f};                                  \
        S = __builtin_amdgcn_mfma_f32_16x16x32_bf16(KREG[s][0], Qf[qg][0], S, 0, 0, 0); \
        S = __builtin_amdgcn_mfma_f32_16x16x32_bf16(KREG[s][1], Qf[qg][1], S, 0, 0, 0); \
        float e0 = fexp2(S[0]);                                               \
        float e1 = fexp2(S[1]);                                               \
        float e2 = fexp2(S[2]);                                               \
        float e3 = fexp2(S[3]);                                               \
        uint2 p; p.x = pk_tr(e0, e1); p.y = pk_tr(e2, e3);                    \
        *(uint2*)&plds[BUF][qg * 16 + lane16][s * 16 + quad * 4] = p;         \
      }                                                                       \
    }                                                                         \
  }

  bf8_t Kc[2][2], Vc[4];
#pragma unroll
  for (int s = 0; s < 2; ++s)
#pragma unroll
    for (int dc = 0; dc < 2; ++dc)
      Kc[s][dc] = *(const bf8_t*)(kb + (size_t)(s * 16 + lane16) * 64 + dc * 32 + quad * 8);
  SSTEP(Kc, 0);
#pragma unroll
  for (int s = 0; s < 2; ++s)
#pragma unroll
    for (int dc = 0; dc < 2; ++dc)
      Kc[s][dc] = *(const bf8_t*)(kb + (size_t)(32 + s * 16 + lane16) * 64 + dc * 32 + quad * 8);
#pragma unroll
  for (int dg = 0; dg < 4; ++dg)
    Vc[dg] = *(const bf8_t*)(vb + (size_t)(dg * 16 + lane16) * 1024 + quad * 8);

  for (int it = 1; it < 32; ++it) {
    const int cb = it & 1, pb = cb ^ 1;
    bf8_t Pf[2];
#pragma unroll
    for (int qg = 0; qg < 2; ++qg)
      Pf[qg] = *(const bf8_t*)&plds[pb][qg * 16 + lane16][quad * 8];
    SSTEP(Kc, cb);                     // P for step it (Kc holds K step it)
    const int kvk = ((it + 1) & 31) * 32;
#pragma unroll
    for (int s = 0; s < 2; ++s)
#pragma unroll
      for (int dc = 0; dc < 2; ++dc)
        Kc[s][dc] = *(const bf8_t*)(kb + (size_t)(kvk + s * 16 + lane16) * 64 + dc * 32 + quad * 8);
    __builtin_amdgcn_s_setprio(1);
#pragma unroll
    for (int dg = 0; dg < 4; ++dg)
#pragma unroll
      for (int qg = 0; qg < 2; ++qg)
        O[dg][qg] = __builtin_amdgcn_mfma_f32_16x16x32_bf16(Vc[dg], Pf[qg], O[dg][qg], 0, 0, 0);
#pragma unroll
    for (int qg = 0; qg < 2; ++qg)
      O4[qg] = __builtin_amdgcn_mfma_f32_16x16x32_bf16(Aone, Pf[qg], O4[qg], 0, 0, 0);
    __builtin_amdgcn_s_setprio(0);
    const int kvv = it * 32;
#pragma unroll
    for (int dg = 0; dg < 4; ++dg)
      Vc[dg] = *(const bf8_t*)(vb + (size_t)(dg * 16 + lane16) * 1024 + kvv + quad * 8);
  }
  {  // epilogue: PV(31), P in buf 1
    bf8_t Pf[2];
#pragma unroll
    for (int qg = 0; qg < 2; ++qg)
      Pf[qg] = *(const bf8_t*)&plds[1][qg * 16 + lane16][quad * 8];
    __builtin_amdgcn_s_setprio(1);
#pragma unroll
    for (int dg = 0; dg < 4; ++dg)
#pragma unroll
      for (int qg = 0; qg < 2; ++qg)
        O[dg][qg] = __builtin_amdgcn_mfma_f32_16x16x32_bf16(Vc[dg], Pf[qg], O[dg][qg], 0, 0, 0);
#pragma unroll
    for (int qg = 0; qg < 2; ++qg)
      O4[qg] = __builtin_amdgcn_mfma_f32_16x16x32_bf16(Aone, Pf[qg], O4[qg], 0, 0, 0);
    __builtin_amdgcn_s_setprio(0);
  }
#undef SSTEP

  // den[q] sits in O4[qg][0] of lanes quad==0, col=lane16 -> broadcast via shfl
  float rden[2];
#pragma unroll
  for (int qg = 0; qg < 2; ++qg) {
    float d = __shfl(O4[qg][0], lane16);
    rden[qg] = 1.f / d;
  }

  __syncthreads();   // all waves done reading plds before aos overwrites
  // ---- write ao tile: rows n, cols c = h*64 + d ----
#pragma unroll
  for (int dg = 0; dg < 4; ++dg)
#pragma unroll
    for (int qg = 0; qg < 2; ++qg) {
      const int c0 = h * 64 + dg * 16 + quad * 4;
      uint2 p;
      p.x = pk_rnd(O[dg][qg][0] * rden[qg], O[dg][qg][1] * rden[qg]);
      p.y = pk_rnd(O[dg][qg][2] * rden[qg], O[dg][qg][3] * rden[qg]);
      *(uint2*)&aos[qg * 16 + lane16][c0] = p;
    }
  __syncthreads();

  // ---- Phase 3: WO gemm from LDS + residual ----
  {
    const unsigned short* Wbase = wob + (size_t)(w * 64 + lane16) * 256 + quad * 8;
    f4_t acc[4][2];
#pragma unroll
    for (int i = 0; i < 4; ++i)
#pragma unroll
      for (int j = 0; j < 2; ++j) acc[i][j] = (f4_t){0.f, 0.f, 0.f, 0.f};
    for (int kc = 0; kc < 256; kc += 32) {
      bf8_t A[4], Bf[2];
#pragma unroll
      for (int og = 0; og < 4; ++og) A[og] = *(const bf8_t*)(Wbase + (size_t)og * 16 * 256 + kc);
#pragma unroll
      for (int ng = 0; ng < 2; ++ng) Bf[ng] = *(const bf8_t*)&aos[ng * 16 + lane16][kc + quad * 8];
#pragma unroll
      for (int og = 0; og < 4; ++og)
#pragma unroll
        for (int ng = 0; ng < 2; ++ng)
          acc[og][ng] = __builtin_amdgcn_mfma_f32_16x16x32_bf16(A[og], Bf[ng], acc[og][ng], 0, 0, 0);
    }
#pragma unroll
    for (int og = 0; og < 4; ++og) {
      float4 g4 = *(const float4*)&gamma[w * 64 + og * 16 + quad * 4];
      const float g[4] = {g4.x, g4.y, g4.z, g4.w};
#pragma unroll
      for (int ng = 0; ng < 2; ++ng) {
        const int n = n0 + ng * 16 + lane16;
#pragma unroll
        for (int r = 0; r < 4; ++r) {
          const int o = w * 64 + og * 16 + quad * 4 + r;
          const size_t ix = ((size_t)(b * 256 + o)) * 4096 + n;
          outp[ix] = x[ix] + g[r] * acc[og][ng][r];
        }
      }
    }
  }
}

extern "C" void kernel_launch(void* const* d_in, const int* in_sizes, int n_in,
                              void* d_out, int out_size, void* d_ws, size_t ws_size,
                              hipStream_t stream) {
  const float* x     = (const float*)d_in[0];
  const float* gnw   = (const float*)d_in[1];
  const float* gnb   = (const float*)d_in[2];
  const float* wq    = (const float*)d_in[3];
  const float* wk    = (const float*)d_in[4];
  const float* wv    = (const float*)d_in[5];
  const float* wo    = (const float*)d_in[6];
  const float* gamma = (const float*)d_in[7];
  float* out = (float*)d_out;
  float* ws  = (float*)d_ws;
  unsigned short* xnT  = (unsigned short*)(ws + WS_XNT);
  unsigned short* xdsT = (unsigned short*)(ws + WS_XDS);
  unsigned short* kbf  = (unsigned short*)(ws + WS_K);
  unsigned short* vtbf = (unsigned short*)(ws + WS_V);
  unsigned short* wqb  = (unsigned short*)(ws + WS_WQB);
  unsigned short* wkvb = (unsigned short*)(ws + WS_WKV);
  unsigned short* wob  = (unsigned short*)(ws + WS_WOB);

  hipMemsetAsync(ws, 0, 256, stream);
  k_prep_stats<<<1152, 256, 0, stream>>>(x, wq, wk, wv, wo, ws + WS_STATS, wqb, wkvb, wob);
  k_xnt<<<dim3(32, 4, 8), 256, 0, stream>>>(x, gnw, gnb, ws + WS_STATS, xnT, xdsT);
  k_gemm_kv<<<dim3(16, 8), 256, 0, stream>>>(wkvb, xdsT, kbf, vtbf);
  k_fused<<<dim3(128, 8), 256, 0, stream>>>(wqb, xnT, kbf, vtbf, wob, x, gamma, out);
}

// Round 2
// 278.929 us; speedup vs baseline: 1.0021x; 1.0021x over previous
//
#include <hip/hip_runtime.h>

// MobileMQA: B=8, C=256, H=W=64, NUM_HEADS=4, hd=64, ds=2
// R9: R8 structure (32-n tile, grid 1024, den-via-ones-MFMA, setprio,
//     coalesced KV/xds stores) but __launch_bounds__(256,3): R8's (256,4)
//     capped unified VGPR+AGPR at 128 -> spill stall (VGPR=64 reported,
//     MfmaUtil 11%). Cap 170 fits the ~150-reg natural demand, 3 blocks/CU.

#define CNT_INV (1.0f/1048576.0f)
#define EPSV 1e-5f
#define QSCALE 0.18033688f   // 0.125 * log2(e): folded into Q; exp becomes v_exp_f32(S)

// workspace layout (float offsets)
#define WS_STATS 0                    // 64
#define WS_XNT   64                   // bf16 xnT [b][n][c]  = 4,194,304 f
#define WS_XDS   4194368              // bf16 xdsT [b][m][c] = 1,048,576 f
#define WS_K     5242944              // bf16 k   [b][m][d]  = 262,144 f
#define WS_V     5505088              // bf16 vT  [b][d][m]  = 262,144 f
#define WS_WQB   5767232              // bf16 wq  [o][c]     = 32,768 f
#define WS_WKV   5800000              // bf16 [wk;wv]        = 16,384 f
#define WS_WOB   5816384              // bf16 wo  [o][c]     = 32,768 f

typedef __attribute__((ext_vector_type(8))) short bf8_t;   // 8 bf16 MFMA A/B frag
typedef __attribute__((ext_vector_type(4))) float f4_t;    // MFMA C/D frag

static __device__ __forceinline__ unsigned fbits(float f) {
  union { float f; unsigned u; } v; v.f = f; return v.u;
}
static __device__ __forceinline__ unsigned short f2bf(float f) {  // RNE
  unsigned u = fbits(f);
  return (unsigned short)((u + 0x7fffu + ((u >> 16) & 1u)) >> 16);
}
static __device__ __forceinline__ unsigned pk_rnd(float a, float b) {
  return __builtin_amdgcn_perm(fbits(b) + 0x8000u, fbits(a) + 0x8000u, 0x07060302u);
}
static __device__ __forceinline__ unsigned pk_tr(float a, float b) {
  return __builtin_amdgcn_perm(fbits(b), fbits(a), 0x07060302u);
}
static __device__ __forceinline__ float bf2f(unsigned short h) {
  union { unsigned u; float f; } v; v.u = ((unsigned)h) << 16; return v.f;
}
static __device__ __forceinline__ float fexp2(float x) {   // 2^x, raw v_exp_f32
  float r; asm("v_exp_f32 %0, %1" : "=v"(r) : "v"(x)); return r;
}

// ---------------- merged: weight prep (blocks >= 512) + stats (blocks < 512) ----------------
__global__ __launch_bounds__(256) void k_prep_stats(const float* __restrict__ x,
                                                    const float* __restrict__ wq,
                                                    const float* __restrict__ wk,
                                                    const float* __restrict__ wv,
                                                    const float* __restrict__ wo,
                                                    float* __restrict__ stats,
                                                    unsigned short* __restrict__ wqb,
                                                    unsigned short* __restrict__ wkvb,
                                                    unsigned short* __restrict__ wob) {
  const int blk = blockIdx.x;
  const int t = threadIdx.x;
  if (blk < 512) {
    const int b = blk >> 6;
    const int chunk = blk & 63;
    const float4* xb = (const float4*)(x + (size_t)b * 1048576 + (size_t)chunk * 16384);
    float s = 0.f, s2 = 0.f;
#pragma unroll
    for (int it = 0; it < 16; ++it) {
      float4 v = xb[it * 256 + t];
      s  += v.x + v.y + v.z + v.w;
      s2 += v.x * v.x + v.y * v.y + v.z * v.z + v.w * v.w;
    }
#pragma unroll
    for (int o = 32; o > 0; o >>= 1) {
      s  += __shfl_down(s, o);
      s2 += __shfl_down(s2, o);
    }
    __shared__ float red[8];
    const int wid = t >> 6;
    if ((t & 63) == 0) { red[wid] = s; red[4 + wid] = s2; }
    __syncthreads();
    if (t == 0) {
      atomicAdd(&stats[b * 2 + 0], red[0] + red[1] + red[2] + red[3]);
      atomicAdd(&stats[b * 2 + 1], red[4] + red[5] + red[6] + red[7]);
    }
  } else {
    const int idx = (blk - 512) * 256 + t;
    if (idx < 65536) wqb[idx] = f2bf(wq[idx]);
    else if (idx < 81920) wkvb[idx - 65536] = f2bf(wk[idx - 65536]);
    else if (idx < 98304) wkvb[idx - 65536] = f2bf(wv[idx - 81920]);
    else if (idx < 163840) wob[idx - 98304] = f2bf(wo[idx - 98304]);
  }
}

// ---------------- normalize + transpose + fused 2x2 pool ----------------
__global__ __launch_bounds__(256) void k_xnt(const float* __restrict__ x,
                                             const float* __restrict__ gnw,
                                             const float* __restrict__ gnb,
                                             const float* __restrict__ stats,
                                             unsigned short* __restrict__ xnT,
                                             unsigned short* __restrict__ xdsT) {
  __shared__ unsigned short T[128][72];   // [n_local][c_local]
  const int t = threadIdx.x;
  const int b = blockIdx.z, c0 = blockIdx.y * 64, hp = blockIdx.x;
  const int n0 = hp * 128;
  const float mu = stats[b * 2 + 0] * CNT_INV;
  const float rstd = rsqrtf(stats[b * 2 + 1] * CNT_INV - mu * mu + EPSV);
  const int n4 = (t & 31) * 4, cl = t >> 5;
#pragma unroll
  for (int p = 0; p < 8; ++p) {
    const int c = c0 + p * 8 + cl;
    const float gw = gnw[c] * rstd;
    const float gb = gnb[c] - mu * rstd * gnw[c];
    float4 v = *(const float4*)&x[(size_t)(b * 256 + c) * 4096 + n0 + n4];
    T[n4 + 0][p * 8 + cl] = f2bf(v.x * gw + gb);
    T[n4 + 1][p * 8 + cl] = f2bf(v.y * gw + gb);
    T[n4 + 2][p * 8 + cl] = f2bf(v.z * gw + gb);
    T[n4 + 3][p * 8 + cl] = f2bf(v.w * gw + gb);
  }
  __syncthreads();
  {  // write xnT: 128 rows x 64 c
    const int r = t >> 1, ch = (t & 1) * 32;
    unsigned short* dst = xnT + ((size_t)b * 4096 + n0 + r) * 256 + c0 + ch;
#pragma unroll
    for (int u = 0; u < 4; ++u)
      *(uint4*)(dst + u * 8) = *(const uint4*)&T[r][ch + u * 8];
  }
  {  // fused pool: 32 m x 64 c — m-row-major thread map for coalesced store
    const int wd = t >> 3, c8 = (t & 7) * 8;
    uint4 u0 = *(const uint4*)&T[2 * wd][c8];
    uint4 u1 = *(const uint4*)&T[2 * wd + 1][c8];
    uint4 u2 = *(const uint4*)&T[64 + 2 * wd][c8];
    uint4 u3 = *(const uint4*)&T[64 + 2 * wd + 1][c8];
    const unsigned* p0 = (const unsigned*)&u0; const unsigned* p1 = (const unsigned*)&u1;
    const unsigned* p2 = (const unsigned*)&u2; const unsigned* p3 = (const unsigned*)&u3;
    unsigned outp[4];
#pragma unroll
    for (int i = 0; i < 4; ++i) {
      float lo = (bf2f((unsigned short)p0[i]) + bf2f((unsigned short)p1[i]) +
                  bf2f((unsigned short)p2[i]) + bf2f((unsigned short)p3[i])) * 0.25f;
      float hi = (bf2f((unsigned short)(p0[i] >> 16)) + bf2f((unsigned short)(p1[i] >> 16)) +
                  bf2f((unsigned short)(p2[i] >> 16)) + bf2f((unsigned short)(p3[i] >> 16))) * 0.25f;
      outp[i] = pk_rnd(lo, hi);
    }
    *(uint4*)(xdsT + ((size_t)b * 1024 + hp * 32 + wd) * 256 + c0 + c8) = *(uint4*)outp;
  }
}

// ---------------- K/V gemm (MFMA): k[b][m][d], vT[b][d][m] bf16, LDS-staged stores ----------------
__global__ __launch_bounds__(256) void k_gemm_kv(const unsigned short* __restrict__ wkvb,
                                                 const unsigned short* __restrict__ xdsT,
                                                 unsigned short* __restrict__ kbf,
                                                 unsigned short* __restrict__ vtbf) {
  __shared__ __align__(16) unsigned short kv[2][64][72];   // [0]=K [m][d], [1]=V [d][m]
  const int t = threadIdx.x;
  const int w = t >> 6, l = t & 63, lane16 = l & 15, quad = l >> 4;
  const int m0 = blockIdx.x * 64, b = blockIdx.y;
  const unsigned short* Abase = wkvb + (size_t)(w * 32 + lane16) * 256 + quad * 8;
  const unsigned short* Bbase = xdsT + ((size_t)b * 1024 + m0 + lane16) * 256 + quad * 8;
  f4_t acc[2][4];
#pragma unroll
  for (int i = 0; i < 2; ++i)
#pragma unroll
    for (int j = 0; j < 4; ++j) acc[i][j] = (f4_t){0.f, 0.f, 0.f, 0.f};
  bf8_t Ac[2], Bc[4];
#pragma unroll
  for (int og = 0; og < 2; ++og) Ac[og] = *(const bf8_t*)(Abase + (size_t)og * 16 * 256);
#pragma unroll
  for (int mg = 0; mg < 4; ++mg) Bc[mg] = *(const bf8_t*)(Bbase + (size_t)mg * 16 * 256);
  for (int kc = 0; kc < 256; kc += 32) {
    const int kn = (kc + 32) & 255;
    bf8_t An[2], Bn[4];
#pragma unroll
    for (int og = 0; og < 2; ++og) An[og] = *(const bf8_t*)(Abase + (size_t)og * 16 * 256 + kn);
#pragma unroll
    for (int mg = 0; mg < 4; ++mg) Bn[mg] = *(const bf8_t*)(Bbase + (size_t)mg * 16 * 256 + kn);
#pragma unroll
    for (int og = 0; og < 2; ++og)
#pragma unroll
      for (int mg = 0; mg < 4; ++mg)
        acc[og][mg] = __builtin_amdgcn_mfma_f32_16x16x32_bf16(Ac[og], Bc[mg], acc[og][mg], 0, 0, 0);
#pragma unroll
    for (int og = 0; og < 2; ++og) Ac[og] = An[og];
#pragma unroll
    for (int mg = 0; mg < 4; ++mg) Bc[mg] = Bn[mg];
  }
  if (w < 2) {  // K tile -> LDS [m][d]
#pragma unroll
    for (int og = 0; og < 2; ++og)
#pragma unroll
      for (int mg = 0; mg < 4; ++mg) {
        uint2 p;
        p.x = pk_rnd(acc[og][mg][0], acc[og][mg][1]);
        p.y = pk_rnd(acc[og][mg][2], acc[og][mg][3]);
        *(uint2*)&kv[0][mg * 16 + lane16][w * 32 + og * 16 + quad * 4] = p;
      }
  } else {  // V tile -> LDS [d][m]
#pragma unroll
    for (int og = 0; og < 2; ++og)
#pragma unroll
      for (int mg = 0; mg < 4; ++mg) {
        const int d0 = (w - 2) * 32 + og * 16 + quad * 4;
#pragma unroll
        for (int r = 0; r < 4; ++r)
          kv[1][d0 + r][mg * 16 + lane16] = f2bf(acc[og][mg][r]);
      }
  }
  __syncthreads();
  {  // coalesced writeout: row = 64 u16 = 8 uint4; thread t -> (row t>>2, 2x uint4)
    const int row = t >> 2, seg = (t & 3) * 16;
    uint4 k0 = *(const uint4*)&kv[0][row][seg];
    uint4 k1 = *(const uint4*)&kv[0][row][seg + 8];
    unsigned short* kd = kbf + (size_t)b * 65536 + (size_t)(m0 + row) * 64 + seg;
    *(uint4*)kd = k0; *(uint4*)(kd + 8) = k1;
    uint4 v0 = *(const uint4*)&kv[1][row][seg];
    uint4 v1 = *(const uint4*)&kv[1][row][seg + 8];
    unsigned short* vd = vtbf + (size_t)b * 65536 + (size_t)row * 1024 + m0 + seg;
    *(uint4*)vd = v0; *(uint4*)(vd + 8) = v1;
  }
}

// ---------------- fused Q-proj + attention + WO + residual ----------------
// block = (b, 32-n tile), wave = head. grid 128x8 = 1024 blocks.
// __launch_bounds__(256,3): cap ~170 regs — natural demand ~150, no spill,
// 3 blocks/CU resident (R8's (256,4) cap=128 spilled: VGPR=64, MfmaUtil 11%).
// LDS phases unioned (20,480 B total):
//   qst  [4][32][72] u16 (18,432 B)  — Q restage, per wave
//   plds [4][2][32][40] u16 (20,480 B) — P double-buffer, per wave
//   aos  [32][264] u16 (16,896 B)    — block-shared ao tile
// den folded into PV: Aone ones-row MFMA accumulates sum(P) in O4[qg][0].
__global__ __launch_bounds__(256, 3) void k_fused(const unsigned short* __restrict__ wqb,
                                                  const unsigned short* __restrict__ xnT,
                                                  const unsigned short* __restrict__ kbf,
                                                  const unsigned short* __restrict__ vtbf,
                                                  const unsigned short* __restrict__ wob,
                                                  const float* __restrict__ x,
                                                  const float* __restrict__ gamma,
                                                  float* __restrict__ outp) {
  __shared__ __align__(16) unsigned short smem[10240];   // 20,480 B
  const int t = threadIdx.x;
  const int w = t >> 6, l = t & 63, lane16 = l & 15, quad = l >> 4;
  const int n0 = blockIdx.x * 32, b = blockIdx.y;
  const int h = w;
  unsigned short* qst = smem + w * 2304;                               // [32][72]
  unsigned short (*plds)[32][40] = (unsigned short (*)[32][40])(smem + w * 2560);
  unsigned short (*aos)[264] = (unsigned short (*)[264])smem;

  const unsigned short* kb = kbf + (size_t)b * 65536;
  const unsigned short* vb = vtbf + (size_t)b * 65536;

  // ---- Phase 1: Q-proj 32q x 64d for this head, restage via LDS ----
  {
    const unsigned short* Abase = wqb + (size_t)(h * 64 + lane16) * 256 + quad * 8;
    const unsigned short* Bbase = xnT + ((size_t)b * 4096 + n0 + lane16) * 256 + quad * 8;
    f4_t qacc[4][2];
#pragma unroll
    for (int i = 0; i < 4; ++i)
#pragma unroll
      for (int j = 0; j < 2; ++j) qacc[i][j] = (f4_t){0.f, 0.f, 0.f, 0.f};
    for (int kc = 0; kc < 256; kc += 32) {
      bf8_t A[4], Bf[2];
#pragma unroll
      for (int og = 0; og < 4; ++og) A[og] = *(const bf8_t*)(Abase + (size_t)og * 16 * 256 + kc);
#pragma unroll
      for (int ng = 0; ng < 2; ++ng) Bf[ng] = *(const bf8_t*)(Bbase + (size_t)ng * 16 * 256 + kc);
#pragma unroll
      for (int og = 0; og < 4; ++og)
#pragma unroll
        for (int ng = 0; ng < 2; ++ng)
          qacc[og][ng] = __builtin_amdgcn_mfma_f32_16x16x32_bf16(A[og], Bf[ng], qacc[og][ng], 0, 0, 0);
    }
    // C-layout (row d = og*16+quad*4+r, col q = ng*16+lane16) -> qst[q][d]
#pragma unroll
    for (int og = 0; og < 4; ++og)
#pragma unroll
      for (int ng = 0; ng < 2; ++ng) {
        uint2 p;
        p.x = pk_rnd(qacc[og][ng][0] * QSCALE, qacc[og][ng][1] * QSCALE);
        p.y = pk_rnd(qacc[og][ng][2] * QSCALE, qacc[og][ng][3] * QSCALE);
        *(uint2*)&qst[(ng * 16 + lane16) * 72 + og * 16 + quad * 4] = p;
      }
  }
  bf8_t Qf[2][2];
#pragma unroll
  for (int qg = 0; qg < 2; ++qg)
#pragma unroll
    for (int dc = 0; dc < 2; ++dc)
      Qf[qg][dc] = *(const bf8_t*)&qst[(qg * 16 + lane16) * 72 + dc * 32 + quad * 8];
  __syncthreads();   // all waves read Q before plds overwrites qst space

  // ---- Phase 2: pipelined attention (PV lags S by one KV step) ----
  f4_t O[4][2];
#pragma unroll
  for (int dg = 0; dg < 4; ++dg)
#pragma unroll
    for (int qg = 0; qg < 2; ++qg) O[dg][qg] = (f4_t){0.f, 0.f, 0.f, 0.f};
  f4_t O4[2];
  O4[0] = (f4_t){0.f, 0.f, 0.f, 0.f};
  O4[1] = (f4_t){0.f, 0.f, 0.f, 0.f};
  // ones-row A fragment: A row = lane16, so lane16==0 (all quads) holds bf16 1.0 x8.
  // Output row 0 (quad0, reg0) accumulates sum_m P[q][m] = softmax denominator.
  const short onebf = (lane16 == 0) ? (short)0x3F80 : (short)0;
  const bf8_t Aone = {onebf, onebf, onebf, onebf, onebf, onebf, onebf, onebf};

#define SSTEP(KREG, BUF)                                                      \
  {                                                                           \
    _Pragma("unroll")                                                         \
    for (int qg = 0; qg < 2; ++qg) {                                          \
      _Pragma("unroll")                                                       \
      for (int s = 0; s < 2; ++s) {                                           \
        f4_t S = (f4_t){0.f, 0.f, 0.f, 0.f};                                  \
        S = __builtin_amdgcn_mfma_f32_16x16x32_bf16(KREG[s][0], Qf[qg][0], S, 0, 0, 0); \
        S = __builtin_amdgcn_mfma_f32_16x16x32_bf16(KREG[s][1], Qf[qg][1], S, 0, 0, 0); \
        float e0 = fexp2(S[0]);                                               \
        float e1 = fexp2(S[1]);                                               \
        float e2 = fexp2(S[2]);                                               \
        float e3 = fexp2(S[3]);                                               \
        uint2 p; p.x = pk_tr(e0, e1); p.y = pk_tr(e2, e3);                    \
        *(uint2*)&plds[BUF][qg * 16 + lane16][s * 16 + quad * 4] = p;         \
      }                                                                       \
    }                                                                         \
  }

  bf8_t Kc[2][2], Vc[4];
#pragma unroll
  for (int s = 0; s < 2; ++s)
#pragma unroll
    for (int dc = 0; dc < 2; ++dc)
      Kc[s][dc] = *(const bf8_t*)(kb + (size_t)(s * 16 + lane16) * 64 + dc * 32 + quad * 8);
  SSTEP(Kc, 0);
#pragma unroll
  for (int s = 0; s < 2; ++s)
#pragma unroll
    for (int dc = 0; dc < 2; ++dc)
      Kc[s][dc] = *(const bf8_t*)(kb + (size_t)(32 + s * 16 + lane16) * 64 + dc * 32 + quad * 8);
#pragma unroll
  for (int dg = 0; dg < 4; ++dg)
    Vc[dg] = *(const bf8_t*)(vb + (size_t)(dg * 16 + lane16) * 1024 + quad * 8);

  for (int it = 1; it < 32; ++it) {
    const int cb = it & 1, pb = cb ^ 1;
    bf8_t Pf[2];
#pragma unroll
    for (int qg = 0; qg < 2; ++qg)
      Pf[qg] = *(const bf8_t*)&plds[pb][qg * 16 + lane16][quad * 8];
    SSTEP(Kc, cb);                     // P for step it (Kc holds K step it)
    const int kvk = ((it + 1) & 31) * 32;
#pragma unroll
    for (int s = 0; s < 2; ++s)
#pragma unroll
      for (int dc = 0; dc < 2; ++dc)
        Kc[s][dc] = *(const bf8_t*)(kb + (size_t)(kvk + s * 16 + lane16) * 64 + dc * 32 + quad * 8);
    __builtin_amdgcn_s_setprio(1);
#pragma unroll
    for (int dg = 0; dg < 4; ++dg)
#pragma unroll
      for (int qg = 0; qg < 2; ++qg)
        O[dg][qg] = __builtin_amdgcn_mfma_f32_16x16x32_bf16(Vc[dg], Pf[qg], O[dg][qg], 0, 0, 0);
#pragma unroll
    for (int qg = 0; qg < 2; ++qg)
      O4[qg] = __builtin_amdgcn_mfma_f32_16x16x32_bf16(Aone, Pf[qg], O4[qg], 0, 0, 0);
    __builtin_amdgcn_s_setprio(0);
    const int kvv = it * 32;
#pragma unroll
    for (int dg = 0; dg < 4; ++dg)
      Vc[dg] = *(const bf8_t*)(vb + (size_t)(dg * 16 + lane16) * 1024 + kvv + quad * 8);
  }
  {  // epilogue: PV(31), P in buf 1
    bf8_t Pf[2];
#pragma unroll
    for (int qg = 0; qg < 2; ++qg)
      Pf[qg] = *(const bf8_t*)&plds[1][qg * 16 + lane16][quad * 8];
    __builtin_amdgcn_s_setprio(1);
#pragma unroll
    for (int dg = 0; dg < 4; ++dg)
#pragma unroll
      for (int qg = 0; qg < 2; ++qg)
        O[dg][qg] = __builtin_amdgcn_mfma_f32_16x16x32_bf16(Vc[dg], Pf[qg], O[dg][qg], 0, 0, 0);
#pragma unroll
    for (int qg = 0; qg < 2; ++qg)
      O4[qg] = __builtin_amdgcn_mfma_f32_16x16x32_bf16(Aone, Pf[qg], O4[qg], 0, 0, 0);
    __builtin_amdgcn_s_setprio(0);
  }
#undef SSTEP

  // den[q] sits in O4[qg][0] of lanes quad==0, col=lane16 -> broadcast via shfl
  float rden[2];
#pragma unroll
  for (int qg = 0; qg < 2; ++qg) {
    float d = __shfl(O4[qg][0], lane16);
    rden[qg] = 1.f / d;
  }

  __syncthreads();   // all waves done reading plds before aos overwrites
  // ---- write ao tile: rows n, cols c = h*64 + d ----
#pragma unroll
  for (int dg = 0; dg < 4; ++dg)
#pragma unroll
    for (int qg = 0; qg < 2; ++qg) {
      const int c0 = h * 64 + dg * 16 + quad * 4;
      uint2 p;
      p.x = pk_rnd(O[dg][qg][0] * rden[qg], O[dg][qg][1] * rden[qg]);
      p.y = pk_rnd(O[dg][qg][2] * rden[qg], O[dg][qg][3] * rden[qg]);
      *(uint2*)&aos[qg * 16 + lane16][c0] = p;
    }
  __syncthreads();

  // ---- Phase 3: WO gemm from LDS + residual ----
  {
    const unsigned short* Wbase = wob + (size_t)(w * 64 + lane16) * 256 + quad * 8;
    f4_t acc[4][2];
#pragma unroll
    for (int i = 0; i < 4; ++i)
#pragma unroll
      for (int j = 0; j < 2; ++j) acc[i][j] = (f4_t){0.f, 0.f, 0.f, 0.f};
    for (int kc = 0; kc < 256; kc += 32) {
      bf8_t A[4], Bf[2];
#pragma unroll
      for (int og = 0; og < 4; ++og) A[og] = *(const bf8_t*)(Wbase + (size_t)og * 16 * 256 + kc);
#pragma unroll
      for (int ng = 0; ng < 2; ++ng) Bf[ng] = *(const bf8_t*)&aos[ng * 16 + lane16][kc + quad * 8];
#pragma unroll
      for (int og = 0; og < 4; ++og)
#pragma unroll
        for (int ng = 0; ng < 2; ++ng)
          acc[og][ng] = __builtin_amdgcn_mfma_f32_16x16x32_bf16(A[og], Bf[ng], acc[og][ng], 0, 0, 0);
    }
#pragma unroll
    for (int og = 0; og < 4; ++og) {
      float4 g4 = *(const float4*)&gamma[w * 64 + og * 16 + quad * 4];
      const float g[4] = {g4.x, g4.y, g4.z, g4.w};
#pragma unroll
      for (int ng = 0; ng < 2; ++ng) {
        const int n = n0 + ng * 16 + lane16;
#pragma unroll
        for (int r = 0; r < 4; ++r) {
          const int o = w * 64 + og * 16 + quad * 4 + r;
          const size_t ix = ((size_t)(b * 256 + o)) * 4096 + n;
          outp[ix] = x[ix] + g[r] * acc[og][ng][r];
        }
      }
    }
  }
}

extern "C" void kernel_launch(void* const* d_in, const int* in_sizes, int n_in,
                              void* d_out, int out_size, void* d_ws, size_t ws_size,
                              hipStream_t stream) {
  const float* x     = (const float*)d_in[0];
  const float* gnw   = (const float*)d_in[1];
  const float* gnb   = (const float*)d_in[2];
  const float* wq    = (const float*)d_in[3];
  const float* wk    = (const float*)d_in[4];
  const float* wv    = (const float*)d_in[5];
  const float* wo    = (const float*)d_in[6];
  const float* gamma = (const float*)d_in[7];
  float* out = (float*)d_out;
  float* ws  = (float*)d_ws;
  unsigned short* xnT  = (unsigned short*)(ws + WS_XNT);
  unsigned short* xdsT = (unsigned short*)(ws + WS_XDS);
  unsigned short* kbf  = (unsigned short*)(ws + WS_K);
  unsigned short* vtbf = (unsigned short*)(ws + WS_V);
  unsigned short* wqb  = (unsigned short*)(ws + WS_WQB);
  unsigned short* wkvb = (unsigned short*)(ws + WS_WKV);
  unsigned short* wob  = (unsigned short*)(ws + WS_WOB);

  hipMemsetAsync(ws, 0, 256, stream);
  k_prep_stats<<<1152, 256, 0, stream>>>(x, wq, wk, wv, wo, ws + WS_STATS, wqb, wkvb, wob);
  k_xnt<<<dim3(32, 4, 8), 256, 0, stream>>>(x, gnw, gnb, ws + WS_STATS, xnT, xdsT);
  k_gemm_kv<<<dim3(16, 8), 256, 0, stream>>>(wkvb, xdsT, kbf, vtbf);
  k_fused<<<dim3(128, 8), 256, 0, stream>>>(wqb, xnT, kbf, vtbf, wob, x, gamma, out);
}

// Round 3
// 217.358 us; speedup vs baseline: 1.2860x; 1.2833x over previous
//
#include <hip/hip_runtime.h>

// MobileMQA: B=8, C=256, H=W=64, NUM_HEADS=4, hd=64, ds=2
// R10: revert to R7 structure (64-n tile, grid 512, wave=head, 102.5us) —
//      R8/R9's 32-n split halved per-iter MFMA with unchanged per-wave K/V
//      loads -> latency-bound (MfmaUtil=VALU=11%). Grafts kept from R8:
//      den folded into PV via ones-row MFMA (kills 16 VALU adds/iter +
//      shfl-xor reduce), s_setprio around PV cluster, coalesced k_gemm_kv
//      writeout (LDS-staged), coalesced k_xnt pooled store.

#define CNT_INV (1.0f/1048576.0f)
#define EPSV 1e-5f
#define QSCALE 0.18033688f   // 0.125 * log2(e): folded into Q; exp becomes v_exp_f32(S)

// workspace layout (float offsets)
#define WS_STATS 0                    // 64
#define WS_XNT   64                   // bf16 xnT [b][n][c]  = 4,194,304 f
#define WS_XDS   4194368              // bf16 xdsT [b][m][c] = 1,048,576 f
#define WS_K     5242944              // bf16 k   [b][m][d]  = 262,144 f
#define WS_V     5505088              // bf16 vT  [b][d][m]  = 262,144 f
#define WS_WQB   5767232              // bf16 wq  [o][c]     = 32,768 f
#define WS_WKV   5800000              // bf16 [wk;wv]        = 16,384 f
#define WS_WOB   5816384              // bf16 wo  [o][c]     = 32,768 f

typedef __attribute__((ext_vector_type(8))) short bf8_t;   // 8 bf16 MFMA A/B frag
typedef __attribute__((ext_vector_type(4))) float f4_t;    // MFMA C/D frag

static __device__ __forceinline__ unsigned fbits(float f) {
  union { float f; unsigned u; } v; v.f = f; return v.u;
}
static __device__ __forceinline__ unsigned short f2bf(float f) {  // RNE
  unsigned u = fbits(f);
  return (unsigned short)((u + 0x7fffu + ((u >> 16) & 1u)) >> 16);
}
static __device__ __forceinline__ unsigned pk_rnd(float a, float b) {
  return __builtin_amdgcn_perm(fbits(b) + 0x8000u, fbits(a) + 0x8000u, 0x07060302u);
}
static __device__ __forceinline__ unsigned pk_tr(float a, float b) {
  return __builtin_amdgcn_perm(fbits(b), fbits(a), 0x07060302u);
}
static __device__ __forceinline__ float bf2f(unsigned short h) {
  union { unsigned u; float f; } v; v.u = ((unsigned)h) << 16; return v.f;
}
static __device__ __forceinline__ float fexp2(float x) {   // 2^x, raw v_exp_f32
  float r; asm("v_exp_f32 %0, %1" : "=v"(r) : "v"(x)); return r;
}

// ---------------- merged: weight prep (blocks >= 512) + stats (blocks < 512) ----------------
__global__ __launch_bounds__(256) void k_prep_stats(const float* __restrict__ x,
                                                    const float* __restrict__ wq,
                                                    const float* __restrict__ wk,
                                                    const float* __restrict__ wv,
                                                    const float* __restrict__ wo,
                                                    float* __restrict__ stats,
                                                    unsigned short* __restrict__ wqb,
                                                    unsigned short* __restrict__ wkvb,
                                                    unsigned short* __restrict__ wob) {
  const int blk = blockIdx.x;
  const int t = threadIdx.x;
  if (blk < 512) {
    const int b = blk >> 6;
    const int chunk = blk & 63;
    const float4* xb = (const float4*)(x + (size_t)b * 1048576 + (size_t)chunk * 16384);
    float s = 0.f, s2 = 0.f;
#pragma unroll
    for (int it = 0; it < 16; ++it) {
      float4 v = xb[it * 256 + t];
      s  += v.x + v.y + v.z + v.w;
      s2 += v.x * v.x + v.y * v.y + v.z * v.z + v.w * v.w;
    }
#pragma unroll
    for (int o = 32; o > 0; o >>= 1) {
      s  += __shfl_down(s, o);
      s2 += __shfl_down(s2, o);
    }
    __shared__ float red[8];
    const int wid = t >> 6;
    if ((t & 63) == 0) { red[wid] = s; red[4 + wid] = s2; }
    __syncthreads();
    if (t == 0) {
      atomicAdd(&stats[b * 2 + 0], red[0] + red[1] + red[2] + red[3]);
      atomicAdd(&stats[b * 2 + 1], red[4] + red[5] + red[6] + red[7]);
    }
  } else {
    const int idx = (blk - 512) * 256 + t;
    if (idx < 65536) wqb[idx] = f2bf(wq[idx]);
    else if (idx < 81920) wkvb[idx - 65536] = f2bf(wk[idx - 65536]);
    else if (idx < 98304) wkvb[idx - 65536] = f2bf(wv[idx - 81920]);
    else if (idx < 163840) wob[idx - 98304] = f2bf(wo[idx - 98304]);
  }
}

// ---------------- normalize + transpose + fused 2x2 pool ----------------
__global__ __launch_bounds__(256) void k_xnt(const float* __restrict__ x,
                                             const float* __restrict__ gnw,
                                             const float* __restrict__ gnb,
                                             const float* __restrict__ stats,
                                             unsigned short* __restrict__ xnT,
                                             unsigned short* __restrict__ xdsT) {
  __shared__ unsigned short T[128][72];   // [n_local][c_local]
  const int t = threadIdx.x;
  const int b = blockIdx.z, c0 = blockIdx.y * 64, hp = blockIdx.x;
  const int n0 = hp * 128;
  const float mu = stats[b * 2 + 0] * CNT_INV;
  const float rstd = rsqrtf(stats[b * 2 + 1] * CNT_INV - mu * mu + EPSV);
  const int n4 = (t & 31) * 4, cl = t >> 5;
#pragma unroll
  for (int p = 0; p < 8; ++p) {
    const int c = c0 + p * 8 + cl;
    const float gw = gnw[c] * rstd;
    const float gb = gnb[c] - mu * rstd * gnw[c];
    float4 v = *(const float4*)&x[(size_t)(b * 256 + c) * 4096 + n0 + n4];
    T[n4 + 0][p * 8 + cl] = f2bf(v.x * gw + gb);
    T[n4 + 1][p * 8 + cl] = f2bf(v.y * gw + gb);
    T[n4 + 2][p * 8 + cl] = f2bf(v.z * gw + gb);
    T[n4 + 3][p * 8 + cl] = f2bf(v.w * gw + gb);
  }
  __syncthreads();
  {  // write xnT: 128 rows x 64 c
    const int r = t >> 1, ch = (t & 1) * 32;
    unsigned short* dst = xnT + ((size_t)b * 4096 + n0 + r) * 256 + c0 + ch;
#pragma unroll
    for (int u = 0; u < 4; ++u)
      *(uint4*)(dst + u * 8) = *(const uint4*)&T[r][ch + u * 8];
  }
  {  // fused pool: 32 m x 64 c — m-row-major thread map for coalesced store
    const int wd = t >> 3, c8 = (t & 7) * 8;
    uint4 u0 = *(const uint4*)&T[2 * wd][c8];
    uint4 u1 = *(const uint4*)&T[2 * wd + 1][c8];
    uint4 u2 = *(const uint4*)&T[64 + 2 * wd][c8];
    uint4 u3 = *(const uint4*)&T[64 + 2 * wd + 1][c8];
    const unsigned* p0 = (const unsigned*)&u0; const unsigned* p1 = (const unsigned*)&u1;
    const unsigned* p2 = (const unsigned*)&u2; const unsigned* p3 = (const unsigned*)&u3;
    unsigned outp[4];
#pragma unroll
    for (int i = 0; i < 4; ++i) {
      float lo = (bf2f((unsigned short)p0[i]) + bf2f((unsigned short)p1[i]) +
                  bf2f((unsigned short)p2[i]) + bf2f((unsigned short)p3[i])) * 0.25f;
      float hi = (bf2f((unsigned short)(p0[i] >> 16)) + bf2f((unsigned short)(p1[i] >> 16)) +
                  bf2f((unsigned short)(p2[i] >> 16)) + bf2f((unsigned short)(p3[i] >> 16))) * 0.25f;
      outp[i] = pk_rnd(lo, hi);
    }
    *(uint4*)(xdsT + ((size_t)b * 1024 + hp * 32 + wd) * 256 + c0 + c8) = *(uint4*)outp;
  }
}

// ---------------- K/V gemm (MFMA): k[b][m][d], vT[b][d][m] bf16, LDS-staged stores ----------------
__global__ __launch_bounds__(256) void k_gemm_kv(const unsigned short* __restrict__ wkvb,
                                                 const unsigned short* __restrict__ xdsT,
                                                 unsigned short* __restrict__ kbf,
                                                 unsigned short* __restrict__ vtbf) {
  __shared__ __align__(16) unsigned short kv[2][64][72];   // [0]=K [m][d], [1]=V [d][m]
  const int t = threadIdx.x;
  const int w = t >> 6, l = t & 63, lane16 = l & 15, quad = l >> 4;
  const int m0 = blockIdx.x * 64, b = blockIdx.y;
  const unsigned short* Abase = wkvb + (size_t)(w * 32 + lane16) * 256 + quad * 8;
  const unsigned short* Bbase = xdsT + ((size_t)b * 1024 + m0 + lane16) * 256 + quad * 8;
  f4_t acc[2][4];
#pragma unroll
  for (int i = 0; i < 2; ++i)
#pragma unroll
    for (int j = 0; j < 4; ++j) acc[i][j] = (f4_t){0.f, 0.f, 0.f, 0.f};
  bf8_t Ac[2], Bc[4];
#pragma unroll
  for (int og = 0; og < 2; ++og) Ac[og] = *(const bf8_t*)(Abase + (size_t)og * 16 * 256);
#pragma unroll
  for (int mg = 0; mg < 4; ++mg) Bc[mg] = *(const bf8_t*)(Bbase + (size_t)mg * 16 * 256);
  for (int kc = 0; kc < 256; kc += 32) {
    const int kn = (kc + 32) & 255;
    bf8_t An[2], Bn[4];
#pragma unroll
    for (int og = 0; og < 2; ++og) An[og] = *(const bf8_t*)(Abase + (size_t)og * 16 * 256 + kn);
#pragma unroll
    for (int mg = 0; mg < 4; ++mg) Bn[mg] = *(const bf8_t*)(Bbase + (size_t)mg * 16 * 256 + kn);
#pragma unroll
    for (int og = 0; og < 2; ++og)
#pragma unroll
      for (int mg = 0; mg < 4; ++mg)
        acc[og][mg] = __builtin_amdgcn_mfma_f32_16x16x32_bf16(Ac[og], Bc[mg], acc[og][mg], 0, 0, 0);
#pragma unroll
    for (int og = 0; og < 2; ++og) Ac[og] = An[og];
#pragma unroll
    for (int mg = 0; mg < 4; ++mg) Bc[mg] = Bn[mg];
  }
  if (w < 2) {  // K tile -> LDS [m][d]
#pragma unroll
    for (int og = 0; og < 2; ++og)
#pragma unroll
      for (int mg = 0; mg < 4; ++mg) {
        uint2 p;
        p.x = pk_rnd(acc[og][mg][0], acc[og][mg][1]);
        p.y = pk_rnd(acc[og][mg][2], acc[og][mg][3]);
        *(uint2*)&kv[0][mg * 16 + lane16][w * 32 + og * 16 + quad * 4] = p;
      }
  } else {  // V tile -> LDS [d][m]
#pragma unroll
    for (int og = 0; og < 2; ++og)
#pragma unroll
      for (int mg = 0; mg < 4; ++mg) {
        const int d0 = (w - 2) * 32 + og * 16 + quad * 4;
#pragma unroll
        for (int r = 0; r < 4; ++r)
          kv[1][d0 + r][mg * 16 + lane16] = f2bf(acc[og][mg][r]);
      }
  }
  __syncthreads();
  {  // coalesced writeout: row = 64 u16 = 8 uint4; thread t -> (row t>>2, 2x uint4)
    const int row = t >> 2, seg = (t & 3) * 16;
    uint4 k0 = *(const uint4*)&kv[0][row][seg];
    uint4 k1 = *(const uint4*)&kv[0][row][seg + 8];
    unsigned short* kd = kbf + (size_t)b * 65536 + (size_t)(m0 + row) * 64 + seg;
    *(uint4*)kd = k0; *(uint4*)(kd + 8) = k1;
    uint4 v0 = *(const uint4*)&kv[1][row][seg];
    uint4 v1 = *(const uint4*)&kv[1][row][seg + 8];
    unsigned short* vd = vtbf + (size_t)b * 65536 + (size_t)row * 1024 + m0 + seg;
    *(uint4*)vd = v0; *(uint4*)(vd + 8) = v1;
  }
}

// ---------------- fused Q-proj + attention + WO + residual ----------------
// block = (b, 64-n tile), wave = head (R7 geometry). LDS phases unioned:
//   qst  [4][64][72] u16 (36,864 B)  — Q restage, per wave
//   plds [4][2][64][40] u16 (40,960 B) — P double-buffer, per wave
//   aos  [64][264] u16 (33,792 B)    — block-shared ao tile
// den folded into PV: Aone ones-row MFMA accumulates sum(P) in O4[qg][0].
__global__ __launch_bounds__(256) void k_fused(const unsigned short* __restrict__ wqb,
                                               const unsigned short* __restrict__ xnT,
                                               const unsigned short* __restrict__ kbf,
                                               const unsigned short* __restrict__ vtbf,
                                               const unsigned short* __restrict__ wob,
                                               const float* __restrict__ x,
                                               const float* __restrict__ gamma,
                                               float* __restrict__ outp) {
  __shared__ __align__(16) unsigned short smem[20480];   // 40,960 B
  const int t = threadIdx.x;
  const int w = t >> 6, l = t & 63, lane16 = l & 15, quad = l >> 4;
  const int n0 = blockIdx.x * 64, b = blockIdx.y;
  const int h = w;
  unsigned short* qst = smem + w * 4608;                               // [64][72]
  unsigned short (*plds)[64][40] = (unsigned short (*)[64][40])(smem + w * 5120);
  unsigned short (*aos)[264] = (unsigned short (*)[264])smem;

  const unsigned short* kb = kbf + (size_t)b * 65536;
  const unsigned short* vb = vtbf + (size_t)b * 65536;

  // ---- Phase 1: Q-proj 64q x 64d for this head, restage via LDS ----
  {
    const unsigned short* Abase = wqb + (size_t)(h * 64 + lane16) * 256 + quad * 8;
    const unsigned short* Bbase = xnT + ((size_t)b * 4096 + n0 + lane16) * 256 + quad * 8;
    f4_t qacc[4][4];
#pragma unroll
    for (int i = 0; i < 4; ++i)
#pragma unroll
      for (int j = 0; j < 4; ++j) qacc[i][j] = (f4_t){0.f, 0.f, 0.f, 0.f};
    for (int kc = 0; kc < 256; kc += 32) {
      bf8_t A[4], Bf[4];
#pragma unroll
      for (int og = 0; og < 4; ++og) A[og] = *(const bf8_t*)(Abase + (size_t)og * 16 * 256 + kc);
#pragma unroll
      for (int ng = 0; ng < 4; ++ng) Bf[ng] = *(const bf8_t*)(Bbase + (size_t)ng * 16 * 256 + kc);
#pragma unroll
      for (int og = 0; og < 4; ++og)
#pragma unroll
        for (int ng = 0; ng < 4; ++ng)
          qacc[og][ng] = __builtin_amdgcn_mfma_f32_16x16x32_bf16(A[og], Bf[ng], qacc[og][ng], 0, 0, 0);
    }
    // C-layout (row d = og*16+quad*4+r, col q = ng*16+lane16) -> qst[q][d]
#pragma unroll
    for (int og = 0; og < 4; ++og)
#pragma unroll
      for (int ng = 0; ng < 4; ++ng) {
        uint2 p;
        p.x = pk_rnd(qacc[og][ng][0] * QSCALE, qacc[og][ng][1] * QSCALE);
        p.y = pk_rnd(qacc[og][ng][2] * QSCALE, qacc[og][ng][3] * QSCALE);
        *(uint2*)&qst[(ng * 16 + lane16) * 72 + og * 16 + quad * 4] = p;
      }
  }
  bf8_t Qf[4][2];
#pragma unroll
  for (int qg = 0; qg < 4; ++qg)
#pragma unroll
    for (int dc = 0; dc < 2; ++dc)
      Qf[qg][dc] = *(const bf8_t*)&qst[(qg * 16 + lane16) * 72 + dc * 32 + quad * 8];
  __syncthreads();   // all waves read Q before plds overwrites qst space

  // ---- Phase 2: pipelined attention (PV lags S by one KV step) ----
  f4_t O[4][4];
#pragma unroll
  for (int dg = 0; dg < 4; ++dg)
#pragma unroll
    for (int qg = 0; qg < 4; ++qg) O[dg][qg] = (f4_t){0.f, 0.f, 0.f, 0.f};
  f4_t O4[4];
#pragma unroll
  for (int qg = 0; qg < 4; ++qg) O4[qg] = (f4_t){0.f, 0.f, 0.f, 0.f};
  // ones-row A fragment: A row = lane16, so lane16==0 (all quads) holds bf16 1.0 x8.
  // Output row 0 (quad0, reg0) accumulates sum_m P[q][m] = softmax denominator.
  const short onebf = (lane16 == 0) ? (short)0x3F80 : (short)0;
  const bf8_t Aone = {onebf, onebf, onebf, onebf, onebf, onebf, onebf, onebf};

#define SSTEP(KREG, BUF)                                                      \
  {                                                                           \
    _Pragma("unroll")                                                         \
    for (int qg = 0; qg < 4; ++qg) {                                          \
      _Pragma("unroll")                                                       \
      for (int s = 0; s < 2; ++s) {                                           \
        f4_t S = (f4_t){0.f, 0.f, 0.f, 0.f};                                  \
        S = __builtin_amdgcn_mfma_f32_16x16x32_bf16(KREG[s][0], Qf[qg][0], S, 0, 0, 0); \
        S = __builtin_amdgcn_mfma_f32_16x16x32_bf16(KREG[s][1], Qf[qg][1], S, 0, 0, 0); \
        float e0 = fexp2(S[0]);                                               \
        float e1 = fexp2(S[1]);                                               \
        float e2 = fexp2(S[2]);                                               \
        float e3 = fexp2(S[3]);                                               \
        uint2 p; p.x = pk_tr(e0, e1); p.y = pk_tr(e2, e3);                    \
        *(uint2*)&plds[BUF][qg * 16 + lane16][s * 16 + quad * 4] = p;         \
      }                                                                       \
    }                                                                         \
  }

  bf8_t Kc[2][2];
#pragma unroll
  for (int s = 0; s < 2; ++s)
#pragma unroll
    for (int dc = 0; dc < 2; ++dc)
      Kc[s][dc] = *(const bf8_t*)(kb + (size_t)(s * 16 + lane16) * 64 + dc * 32 + quad * 8);
  SSTEP(Kc, 0);

  bf8_t Vc[4];
#pragma unroll
  for (int s = 0; s < 2; ++s)
#pragma unroll
    for (int dc = 0; dc < 2; ++dc)
      Kc[s][dc] = *(const bf8_t*)(kb + (size_t)(32 + s * 16 + lane16) * 64 + dc * 32 + quad * 8);
#pragma unroll
  for (int dg = 0; dg < 4; ++dg)
    Vc[dg] = *(const bf8_t*)(vb + (size_t)(dg * 16 + lane16) * 1024 + quad * 8);

  for (int it = 1; it < 32; ++it) {
    const int cb = it & 1, pb = cb ^ 1;
    bf8_t Pf[4];
#pragma unroll
    for (int qg = 0; qg < 4; ++qg)
      Pf[qg] = *(const bf8_t*)&plds[pb][qg * 16 + lane16][quad * 8];
    const int kvk = ((it + 1) & 31) * 32;
    const int kvv = it * 32;
    bf8_t K2[2][2], V2[4];
#pragma unroll
    for (int s = 0; s < 2; ++s)
#pragma unroll
      for (int dc = 0; dc < 2; ++dc)
        K2[s][dc] = *(const bf8_t*)(kb + (size_t)(kvk + s * 16 + lane16) * 64 + dc * 32 + quad * 8);
#pragma unroll
    for (int dg = 0; dg < 4; ++dg)
      V2[dg] = *(const bf8_t*)(vb + (size_t)(dg * 16 + lane16) * 1024 + kvv + quad * 8);
    __builtin_amdgcn_s_setprio(1);
#pragma unroll
    for (int dg = 0; dg < 4; ++dg)
#pragma unroll
      for (int qg = 0; qg < 4; ++qg)
        O[dg][qg] = __builtin_amdgcn_mfma_f32_16x16x32_bf16(Vc[dg], Pf[qg], O[dg][qg], 0, 0, 0);
#pragma unroll
    for (int qg = 0; qg < 4; ++qg)
      O4[qg] = __builtin_amdgcn_mfma_f32_16x16x32_bf16(Aone, Pf[qg], O4[qg], 0, 0, 0);
    __builtin_amdgcn_s_setprio(0);
    SSTEP(Kc, cb);
#pragma unroll
    for (int s = 0; s < 2; ++s)
#pragma unroll
      for (int dc = 0; dc < 2; ++dc) Kc[s][dc] = K2[s][dc];
#pragma unroll
    for (int dg = 0; dg < 4; ++dg) Vc[dg] = V2[dg];
  }
  {  // epilogue: PV(31), P in buf 1
    bf8_t Pf[4];
#pragma unroll
    for (int qg = 0; qg < 4; ++qg)
      Pf[qg] = *(const bf8_t*)&plds[1][qg * 16 + lane16][quad * 8];
    __builtin_amdgcn_s_setprio(1);
#pragma unroll
    for (int dg = 0; dg < 4; ++dg)
#pragma unroll
      for (int qg = 0; qg < 4; ++qg)
        O[dg][qg] = __builtin_amdgcn_mfma_f32_16x16x32_bf16(Vc[dg], Pf[qg], O[dg][qg], 0, 0, 0);
#pragma unroll
    for (int qg = 0; qg < 4; ++qg)
      O4[qg] = __builtin_amdgcn_mfma_f32_16x16x32_bf16(Aone, Pf[qg], O4[qg], 0, 0, 0);
    __builtin_amdgcn_s_setprio(0);
  }
#undef SSTEP

  // den[q] sits in O4[qg][0] of lanes quad==0, col=lane16 -> broadcast via shfl
  float rden[4];
#pragma unroll
  for (int qg = 0; qg < 4; ++qg) {
    float d = __shfl(O4[qg][0], lane16);
    rden[qg] = 1.f / d;
  }

  __syncthreads();   // all waves done reading plds before aos overwrites
  // ---- write ao tile: rows n, cols c = h*64 + d ----
#pragma unroll
  for (int dg = 0; dg < 4; ++dg)
#pragma unroll
    for (int qg = 0; qg < 4; ++qg) {
      const int c0 = h * 64 + dg * 16 + quad * 4;
      uint2 p;
      p.x = pk_rnd(O[dg][qg][0] * rden[qg], O[dg][qg][1] * rden[qg]);
      p.y = pk_rnd(O[dg][qg][2] * rden[qg], O[dg][qg][3] * rden[qg]);
      *(uint2*)&aos[qg * 16 + lane16][c0] = p;
    }
  __syncthreads();

  // ---- Phase 3: WO gemm from LDS + residual ----
  {
    const unsigned short* Wbase = wob + (size_t)(w * 64 + lane16) * 256 + quad * 8;
    f4_t acc[4][4];
#pragma unroll
    for (int i = 0; i < 4; ++i)
#pragma unroll
      for (int j = 0; j < 4; ++j) acc[i][j] = (f4_t){0.f, 0.f, 0.f, 0.f};
    for (int kc = 0; kc < 256; kc += 32) {
      bf8_t A[4], Bf[4];
#pragma unroll
      for (int og = 0; og < 4; ++og) A[og] = *(const bf8_t*)(Wbase + (size_t)og * 16 * 256 + kc);
#pragma unroll
      for (int ng = 0; ng < 4; ++ng) Bf[ng] = *(const bf8_t*)&aos[ng * 16 + lane16][kc + quad * 8];
#pragma unroll
      for (int og = 0; og < 4; ++og)
#pragma unroll
        for (int ng = 0; ng < 4; ++ng)
          acc[og][ng] = __builtin_amdgcn_mfma_f32_16x16x32_bf16(A[og], Bf[ng], acc[og][ng], 0, 0, 0);
    }
#pragma unroll
    for (int og = 0; og < 4; ++og) {
      float4 g4 = *(const float4*)&gamma[w * 64 + og * 16 + quad * 4];
      const float g[4] = {g4.x, g4.y, g4.z, g4.w};
#pragma unroll
      for (int ng = 0; ng < 4; ++ng) {
        const int n = n0 + ng * 16 + lane16;
#pragma unroll
        for (int r = 0; r < 4; ++r) {
          const int o = w * 64 + og * 16 + quad * 4 + r;
          const size_t ix = ((size_t)(b * 256 + o)) * 4096 + n;
          outp[ix] = x[ix] + g[r] * acc[og][ng][r];
        }
      }
    }
  }
}

extern "C" void kernel_launch(void* const* d_in, const int* in_sizes, int n_in,
                              void* d_out, int out_size, void* d_ws, size_t ws_size,
                              hipStream_t stream) {
  const float* x     = (const float*)d_in[0];
  const float* gnw   = (const float*)d_in[1];
  const float* gnb   = (const float*)d_in[2];
  const float* wq    = (const float*)d_in[3];
  const float* wk    = (const float*)d_in[4];
  const float* wv    = (const float*)d_in[5];
  const float* wo    = (const float*)d_in[6];
  const float* gamma = (const float*)d_in[7];
  float* out = (float*)d_out;
  float* ws  = (float*)d_ws;
  unsigned short* xnT  = (unsigned short*)(ws + WS_XNT);
  unsigned short* xdsT = (unsigned short*)(ws + WS_XDS);
  unsigned short* kbf  = (unsigned short*)(ws + WS_K);
  unsigned short* vtbf = (unsigned short*)(ws + WS_V);
  unsigned short* wqb  = (unsigned short*)(ws + WS_WQB);
  unsigned short* wkvb = (unsigned short*)(ws + WS_WKV);
  unsigned short* wob  = (unsigned short*)(ws + WS_WOB);

  hipMemsetAsync(ws, 0, 256, stream);
  k_prep_stats<<<1152, 256, 0, stream>>>(x, wq, wk, wv, wo, ws + WS_STATS, wqb, wkvb, wob);
  k_xnt<<<dim3(32, 4, 8), 256, 0, stream>>>(x, gnw, gnb, ws + WS_STATS, xnT, xdsT);
  k_gemm_kv<<<dim3(16, 8), 256, 0, stream>>>(wkvb, xdsT, kbf, vtbf);
  k_fused<<<dim3(64, 8), 256, 0, stream>>>(wqb, xnT, kbf, vtbf, wob, x, gamma, out);
}